// Round 5
// baseline (1400.741 us; speedup 1.0000x reference)
//
#include <hip/hip_runtime.h>
#include <math.h>

#define HDIM   7168
#define NEXP   256
#define NGROUP 8
#define EPG    32
#define TOPKG  4
#define TOPK   8
#define RSF    2.5

#define BK     32
#define KQLEN  1792         // k per quarter
#define NCHQ   56           // 32-k chunks per K-quarter
#define NB_REF 512          // refine fast-path token cap

// fp32 accumulation + per-ks fold of the lo-correction: logit sigma ~6e-7.
#define TAU    4e-6f
#define TAUG   4e-6f

#define BUFSZ  65536        // A hi 16K | A lo 16K | B hi 16K | B lo 16K

typedef _Float16 f16x8 __attribute__((ext_vector_type(8)));
typedef float    f32x16 __attribute__((ext_vector_type(16)));

// ws layout (bytes):
//   0        cnt (int)
//   256      list (16384 int)
//   66048    khi image: 224 chunks x 16384 B   ([c][u(4)][col(256)][8 f16])
//   3736064  klo image: same
//   7406080  fp32 partial logits [kq(4)][T][256] (67.1 MB), ALIASED by refine
#define WS_CNT_OFF   0
#define WS_LIST_OFF  256
#define WS_KHI_OFF   66048
#define WS_KLO_OFF   3736064
#define WS_BUF_OFF   7406080
#define WS_NEED      (7406080ULL + 67108864ULL)

__device__ __forceinline__ void gload_lds16(const void* g, void* l) {
    __builtin_amdgcn_global_load_lds(
        (const __attribute__((address_space(1))) unsigned int*)g,
        (__attribute__((address_space(3))) unsigned int*)(unsigned long long)(uintptr_t)l,
        16, 0, 0);
}

// ---------------- prep: split + relayout gate matrix, zero counter ----------
__global__ __launch_bounds__(256) void moe_prep(
    const float* __restrict__ wk, char* __restrict__ khi, char* __restrict__ klo,
    int* __restrict__ cnt)
{
    if (blockIdx.x == 0 && threadIdx.x == 0) *cnt = 0;
    const int c   = blockIdx.x;    // global 32-k chunk 0..223
    const int col = threadIdx.x;
    const long cb = (long)c * 16384 + (long)col * 16;
#pragma unroll
    for (int u = 0; u < 4; ++u) {
        f16x8 h8, l8;
#pragma unroll
        for (int h = 0; h < 8; ++h) {
            float v = wk[(long)(c * 32 + u * 8 + h) * NEXP + col];
            _Float16 hi = (_Float16)v;
            h8[h] = hi;
            l8[h] = (_Float16)((v - (float)hi) * 2048.0f);
        }
        *(f16x8*)(khi + cb + u * 4096) = h8;
        *(f16x8*)(klo + cb + u * 4096) = l8;
    }
}

// ---------------- main: split-K/4 split-f16 MFMA GEMM -> fp32 partials ------
// v3: 256-token x 256-expert block tile, 8 waves of 128x64 (0.5 ds_read_b128
// per MFMA vs 0.67 in v2 -> LDS pipe off the critical path), K in quarters so
// each XCD's resident B slice is 1.83 MB (L2-fit under x streaming). The lo
// correction is folded per-ks into the fp32 acc (16 VALU fma, parallel pipe)
// so the accumulator fits: 128 acc VGPR + 16 tmp. Double-buffered LDS,
// depth-1 B prefetch, counted vmcnt(4) barriers (x prefetch stays in flight).
// grid 256 = 64 token-groups x 4 K-quarters; quarter pinned to XCD pairs.
__global__ __launch_bounds__(512, 2) void moe_main(
    const float* __restrict__ x, const char* __restrict__ khi,
    const char* __restrict__ klo, float* __restrict__ logits, int T)
{
    __shared__ __align__(16) char smem[2 * BUFSZ];

    const int tid  = threadIdx.x;
    const int w    = tid >> 6;
    const int l    = tid & 63;
    const int l31  = l & 31;
    const int half = l >> 5;
    const int mg   = w & 1;          // rows mg*128
    const int ng   = w >> 1;         // cols ng*64
    const int bid  = blockIdx.x;
    const int xcd  = bid & 7;
    const int kq   = xcd >> 1;       // K-quarter, 2 XCDs each
    const int tg   = ((bid >> 3) << 1) | (xcd & 1);   // 0..63
    const long t0  = (long)tg * 256;
    const int cg0  = kq * NCHQ;

    // staging roles: thread -> (row = tid>>1, 16 consecutive k at ubase*8)
    const int srow = tid >> 1;
    const int ub   = (tid & 1) * 2;
    const int t16  = tid << 4;
    const int adst = ub * 4096 + srow * 16;   // A image [u(4)][row(256)][16B]
    const float* xp = x + (t0 + srow) * HDIM + (long)kq * KQLEN + ub * 8;

    f32x16 acc[4][2];
#pragma unroll
    for (int i = 0; i < 4; ++i)
#pragma unroll
        for (int j = 0; j < 2; ++j)
#pragma unroll
            for (int r = 0; r < 16; ++r) acc[i][j][r] = 0.f;

    char* cur = smem;
    char* nxt = smem + BUFSZ;

    float4 xr0, xr1, xr2, xr3;

    // ---- prologue ----
    xr0 = *(const float4*)(xp + 0);
    xr1 = *(const float4*)(xp + 4);
    xr2 = *(const float4*)(xp + 8);
    xr3 = *(const float4*)(xp + 12);
    {   // stage A(0) -> cur  (waits the 4 x loads via compiler vmcnt)
        float f[16] = {xr0.x, xr0.y, xr0.z, xr0.w, xr1.x, xr1.y, xr1.z, xr1.w,
                       xr2.x, xr2.y, xr2.z, xr2.w, xr3.x, xr3.y, xr3.z, xr3.w};
        f16x8 h0, l0_, h1, l1_;
#pragma unroll
        for (int i = 0; i < 8; ++i) {
            _Float16 h = (_Float16)f[i];      h0[i] = h;
            l0_[i] = (_Float16)((f[i] - (float)h) * 2048.0f);
            _Float16 g = (_Float16)f[8 + i];  h1[i] = g;
            l1_[i] = (_Float16)((f[8 + i] - (float)g) * 2048.0f);
        }
        *(f16x8*)(cur + adst)                = h0;
        *(f16x8*)(cur + adst + 4096)         = h1;
        *(f16x8*)(cur + 16384 + adst)        = l0_;
        *(f16x8*)(cur + 16384 + adst + 4096) = l1_;
    }
    {   // B(0) DMA -> cur
        const long cb = (long)cg0 * 16384;
        gload_lds16(khi + cb + t16,        cur + 32768 + t16);
        gload_lds16(khi + cb + 8192 + t16, cur + 40960 + t16);
        gload_lds16(klo + cb + t16,        cur + 49152 + t16);
        gload_lds16(klo + cb + 8192 + t16, cur + 57344 + t16);
    }
    asm volatile("" ::: "memory");   // pin order: B DMAs before x prefetch
    xr0 = *(const float4*)(xp + BK + 0);
    xr1 = *(const float4*)(xp + BK + 4);
    xr2 = *(const float4*)(xp + BK + 8);
    xr3 = *(const float4*)(xp + BK + 12);
    // drain B(0) (oldest 4); keep x(1) in flight
    asm volatile("s_waitcnt vmcnt(4) lgkmcnt(0)\n\ts_barrier" ::: "memory");

    for (int c = 0; c < NCHQ; ++c) {
        if (c + 1 < NCHQ) {
            // stage A(c+1) from regs -> nxt
            float f[16] = {xr0.x, xr0.y, xr0.z, xr0.w, xr1.x, xr1.y, xr1.z, xr1.w,
                           xr2.x, xr2.y, xr2.z, xr2.w, xr3.x, xr3.y, xr3.z, xr3.w};
            f16x8 h0, l0_, h1, l1_;
#pragma unroll
            for (int i = 0; i < 8; ++i) {
                _Float16 h = (_Float16)f[i];      h0[i] = h;
                l0_[i] = (_Float16)((f[i] - (float)h) * 2048.0f);
                _Float16 g = (_Float16)f[8 + i];  h1[i] = g;
                l1_[i] = (_Float16)((f[8 + i] - (float)g) * 2048.0f);
            }
            *(f16x8*)(nxt + adst)                = h0;
            *(f16x8*)(nxt + adst + 4096)         = h1;
            *(f16x8*)(nxt + 16384 + adst)        = l0_;
            *(f16x8*)(nxt + 16384 + adst + 4096) = l1_;
            // B(c+1) DMA -> nxt
            const long cb = (long)(cg0 + c + 1) * 16384;
            gload_lds16(khi + cb + t16,        nxt + 32768 + t16);
            gload_lds16(khi + cb + 8192 + t16, nxt + 40960 + t16);
            gload_lds16(klo + cb + t16,        nxt + 49152 + t16);
            gload_lds16(klo + cb + 8192 + t16, nxt + 57344 + t16);
            asm volatile("" ::: "memory");  // pin order: DMAs before x loads
            if (c + 2 < NCHQ) {
                const float* xs = xp + (long)(c + 2) * BK;
                xr0 = *(const float4*)(xs + 0);
                xr1 = *(const float4*)(xs + 4);
                xr2 = *(const float4*)(xs + 8);
                xr3 = *(const float4*)(xs + 12);
            }
        }

        // compute chunk c from cur
#pragma unroll
        for (int ks = 0; ks < 2; ++ks) {
            const int u = ks * 2 + half;
            const char* Ah = cur + u * 4096;
            const char* Al = cur + 16384 + u * 4096;
            const char* Bh = cur + 32768 + u * 4096;
            const char* Bl = cur + 49152 + u * 4096;
            f16x8 ah[4], al[4], bh[2], bl[2];
#pragma unroll
            for (int rs = 0; rs < 4; ++rs) {
                ah[rs] = *(const f16x8*)(Ah + (mg * 128 + rs * 32 + l31) * 16);
                al[rs] = *(const f16x8*)(Al + (mg * 128 + rs * 32 + l31) * 16);
            }
#pragma unroll
            for (int cs = 0; cs < 2; ++cs) {
                bh[cs] = *(const f16x8*)(Bh + (ng * 64 + cs * 32 + l31) * 16);
                bl[cs] = *(const f16x8*)(Bl + (ng * 64 + cs * 32 + l31) * 16);
            }
            __builtin_amdgcn_s_setprio(1);
#pragma unroll
            for (int rs = 0; rs < 4; ++rs)
#pragma unroll
                for (int cs = 0; cs < 2; ++cs)
                    acc[rs][cs] = __builtin_amdgcn_mfma_f32_32x32x16_f16(
                        ah[rs], bh[cs], acc[rs][cs], 0, 0, 0);
#pragma unroll
            for (int rs = 0; rs < 4; ++rs)
#pragma unroll
                for (int cs = 0; cs < 2; ++cs) {
                    f32x16 z;
#pragma unroll
                    for (int r = 0; r < 16; ++r) z[r] = 0.f;
                    z = __builtin_amdgcn_mfma_f32_32x32x16_f16(ah[rs], bl[cs], z, 0, 0, 0);
                    z = __builtin_amdgcn_mfma_f32_32x32x16_f16(al[rs], bh[cs], z, 0, 0, 0);
#pragma unroll
                    for (int r = 0; r < 16; ++r)
                        acc[rs][cs][r] = fmaf(z[r], 4.8828125e-4f, acc[rs][cs][r]);
                }
            __builtin_amdgcn_s_setprio(0);
        }

        // barrier: drain B(c+1) (oldest 4); x(c+2) stays in flight
        if (c + 2 < NCHQ) {
            asm volatile("s_waitcnt vmcnt(4) lgkmcnt(0)\n\ts_barrier" ::: "memory");
        } else if (c + 1 < NCHQ) {
            asm volatile("s_waitcnt vmcnt(0) lgkmcnt(0)\n\ts_barrier" ::: "memory");
        }
        char* tp = cur; cur = nxt; nxt = tp;
    }

    // epilogue (C layout: col=lane&31, row=(r&3)+8*(r>>2)+4*half per subtile)
    float* lg = logits + (long)kq * T * NEXP;
    const long trow = t0 + mg * 128;
    const int  col0 = ng * 64 + l31;
#pragma unroll
    for (int rs = 0; rs < 4; ++rs)
#pragma unroll
        for (int cs = 0; cs < 2; ++cs)
#pragma unroll
            for (int r = 0; r < 16; ++r) {
                const int lrow = (r & 3) + 8 * (r >> 2) + 4 * half;
                const long tok = trow + rs * 32 + lrow;
                lg[tok * NEXP + col0 + cs * 32] = acc[rs][cs][r];
            }
}

// ---------------- gate: reduce quarters, sigmoid+bias, grouped top-k --------
__global__ __launch_bounds__(256) void moe_gate(
    const float* __restrict__ logits, const float* __restrict__ bias,
    float* __restrict__ out, int* __restrict__ cnt, int* __restrict__ list, int T)
{
    __shared__ float sc[64 * 257];
    const int e  = threadIdx.x;
    const long t0 = (long)blockIdx.x * 64;
    const float b = bias[e];
    const long qs = (long)T * NEXP;
    const float* l0 = logits + t0 * NEXP + e;
    for (int tt = 0; tt < 64; ++tt) {
        const long o = (long)tt * NEXP;
        float lg = (l0[o] + l0[qs + o]) + (l0[2 * qs + o] + l0[3 * qs + o]);
        sc[tt * 257 + e] = 1.0f / (1.0f + expf(-lg)) + b;
    }
    __syncthreads();

    if (e < 64) {
        float* row = sc + e * 257;

        float gsum[NGROUP];
#pragma unroll
        for (int g = 0; g < NGROUP; ++g) {
            float m1 = -1e30f, m2 = -1e30f;
            for (int j = 0; j < EPG; ++j) {
                float v = row[g * EPG + j];
                if (v > m1) { m2 = m1; m1 = v; }
                else if (v > m2) { m2 = v; }
            }
            gsum[g] = m1 + m2;
        }

        bool gsel[NGROUP];
#pragma unroll
        for (int g = 0; g < NGROUP; ++g) gsel[g] = false;
        float g4 = 0.0f;
        for (int r = 0; r < TOPKG; ++r) {
            float best = -1e30f; int bi = 0;
            for (int g = 0; g < NGROUP; ++g)
                if (!gsel[g] && gsum[g] > best) { best = gsum[g]; bi = g; }
            gsel[bi] = true; g4 = best;
        }
        float g5 = -1e30f;
        for (int g = 0; g < NGROUP; ++g)
            if (!gsel[g] && gsum[g] > g5) g5 = gsum[g];
        const float margin_g = g4 - g5;

        for (int e2 = 0; e2 < NEXP; ++e2)
            if (!gsel[e2 >> 5]) row[e2] = 0.0f;

        int   id[TOPK];
        float wv[TOPK];
        float wsum = 0.0f;
        for (int r = 0; r < TOPK; ++r) {
            float best = -1e30f; int bi = 0;
            for (int e2 = 0; e2 < NEXP; ++e2) {
                float v = row[e2];
                if (v > best) { best = v; bi = e2; }
            }
            row[bi] = -1e30f;
            id[r] = bi; wv[r] = best; wsum += best;
        }
        float s9 = -1e30f;
        for (int e2 = 0; e2 < NEXP; ++e2)
            if (row[e2] > s9) s9 = row[e2];

        float mmin = wv[TOPK - 1] - s9;
#pragma unroll
        for (int r = 0; r < TOPK - 1; ++r) {
            float d = wv[r] - wv[r + 1];
            if (d < mmin) mmin = d;
        }

        const float inv = 2.5f / (wsum + 1e-20f);
        const long base  = (t0 + e) * TOPK;
        const long wbase = (long)T * TOPK + base;
#pragma unroll
        for (int r = 0; r < TOPK; ++r) {
            out[base + r]  = (float)id[r];
            out[wbase + r] = wv[r] * inv;
        }

        if (mmin < TAU || margin_g < TAUG) {
            int p2 = atomicAdd(cnt, 1);
            if (p2 < T) list[p2] = (int)(t0 + e);
        }
    }
}

// ---------------- shared f64 selection ----------------
__device__ void select_f64(double* sd, int t, float* out, int T) {
    double gsum[NGROUP];
    for (int g = 0; g < NGROUP; ++g) {
        double m1 = -1e300, m2 = -1e300;
        for (int j = 0; j < EPG; ++j) {
            double v = sd[g * EPG + j];
            if (v > m1) { m2 = m1; m1 = v; }
            else if (v > m2) { m2 = v; }
        }
        gsum[g] = m1 + m2;
    }
    bool gsel[NGROUP];
    for (int g = 0; g < NGROUP; ++g) gsel[g] = false;
    for (int r = 0; r < TOPKG; ++r) {
        double best = -1e300; int bi = 0;
        for (int g = 0; g < NGROUP; ++g)
            if (!gsel[g] && gsum[g] > best) { best = gsum[g]; bi = g; }
        gsel[bi] = true;
    }
    for (int e2 = 0; e2 < NEXP; ++e2)
        if (!gsel[e2 >> 5]) sd[e2] = 0.0;

    int id[TOPK]; double wv[TOPK]; double wsum = 0.0;
    for (int r = 0; r < TOPK; ++r) {
        double best = -1e300; int bi = 0;
        for (int e2 = 0; e2 < NEXP; ++e2) {
            double v = sd[e2];
            if (v > best) { best = v; bi = e2; }
        }
        sd[bi] = -1e300;
        id[r] = bi; wv[r] = best; wsum += best;
    }
    const double inv = RSF / (wsum + 1e-20);
    const long base  = (long)t * TOPK;
    const long wbase = (long)T * TOPK + base;
    for (int r = 0; r < TOPK; ++r) {
        out[base + r]  = (float)id[r];
        out[wbase + r] = (float)(wv[r] * inv);
    }
}

// ---------------- refine stage A: fp64 partials, wk read ~once --------------
__global__ __launch_bounds__(256) void moe_refineA(
    const float* __restrict__ x, const float* __restrict__ wk,
    double* __restrict__ pref, const int* __restrict__ cnt,
    const int* __restrict__ list, int T)
{
    __shared__ float xb[8][224];
    int n = *cnt; if (n > T) n = T;
    int nb = n < NB_REF ? n : NB_REF;
    const int kc = blockIdx.x >> 3;
    const int tg = blockIdx.x & 7;
    const int e  = threadIdx.x;

    for (int jb = tg; jb < nb; jb += 64) {
        for (int i = 0; i < 8; ++i) {
            int j = jb + 8 * i;
            if (j >= nb) break;
            if (e < 56) {
                const float* xp = x + (long)list[j] * HDIM + kc * 224 + e * 4;
                *(float4*)&xb[i][e * 4] = *(const float4*)xp;
            }
        }
        __syncthreads();

        double acc[8];
#pragma unroll
        for (int i = 0; i < 8; ++i) acc[i] = 0.0;
        const float* wp = wk + (long)(kc * 224) * NEXP + e;
#pragma unroll 4
        for (int k = 0; k < 224; ++k) {
            double wv = (double)wp[(long)k * NEXP];
#pragma unroll
            for (int i = 0; i < 8; ++i)
                acc[i] = fma((double)xb[i][k], wv, acc[i]);
        }
        for (int i = 0; i < 8; ++i) {
            int j = jb + 8 * i;
            if (j < nb) pref[((long)j * 32 + kc) * NEXP + e] = acc[i];
        }
        __syncthreads();
    }
}

// ---------------- refine stage B: reduce + exact select ---------------------
__global__ __launch_bounds__(256) void moe_refineB(
    const float* __restrict__ x, const float* __restrict__ wk,
    const float* __restrict__ bias, float* __restrict__ out,
    const double* __restrict__ pref, const int* __restrict__ cnt,
    const int* __restrict__ list, int T)
{
    __shared__ double sd[NEXP];
    int n = *cnt; if (n > T) n = T;
    int nb = n < NB_REF ? n : NB_REF;
    const int e = threadIdx.x;
    const int i = blockIdx.x;

    const int t = (i < nb) ? list[i] : -1;
    double s = 0.0;
    if (t >= 0) {
        const double* pp = pref + (long)i * 32 * NEXP + e;
#pragma unroll
        for (int kc = 0; kc < 32; ++kc) s += pp[kc * NEXP];
    }
    sd[e] = (t >= 0) ? (1.0 / (1.0 + exp(-s)) + (double)bias[e]) : 0.0;
    __syncthreads();
    if (t >= 0 && e == 0) select_f64(sd, t, out, T);
    __syncthreads();

    // overflow fallback (n > NB_REF): slow exact per-token — expected never
    for (int j = NB_REF + i; j < n; j += 512) {
        const int tt = list[j];
        const float* xr = x + (long)tt * HDIM;
        double a0 = 0.0, a1 = 0.0;
        for (int k = 0; k < HDIM; k += 2) {
            a0 = fma((double)xr[k],     (double)wk[(long)k * NEXP + e],       a0);
            a1 = fma((double)xr[k + 1], (double)wk[(long)(k + 1) * NEXP + e], a1);
        }
        sd[e] = 1.0 / (1.0 + exp(-(a0 + a1))) + (double)bias[e];
        __syncthreads();
        if (e == 0) select_f64(sd, tt, out, T);
        __syncthreads();
    }
}

// ---------------- fallback: full fp64 (used only if ws too small) -----------
__global__ __launch_bounds__(256) void moe_gate_f64_full(
    const float* __restrict__ x, const float* __restrict__ wk,
    const float* __restrict__ bias, float* __restrict__ out, int T)
{
    __shared__ double sc[16][NEXP + 1];
    const int  e  = threadIdx.x;
    const long t0 = (long)blockIdx.x * 16;
    const float* xb = x + t0 * HDIM;
    double acc[16];
#pragma unroll
    for (int t = 0; t < 16; ++t) acc[t] = 0.0;
    for (int k = 0; k < HDIM; k += 4) {
        double kv0 = (double)wk[(long)(k + 0) * NEXP + e];
        double kv1 = (double)wk[(long)(k + 1) * NEXP + e];
        double kv2 = (double)wk[(long)(k + 2) * NEXP + e];
        double kv3 = (double)wk[(long)(k + 3) * NEXP + e];
#pragma unroll
        for (int t = 0; t < 16; ++t) {
            const float* xr = xb + (long)t * HDIM + k;
            double a = acc[t];
            a = fma((double)xr[0], kv0, a);
            a = fma((double)xr[1], kv1, a);
            a = fma((double)xr[2], kv2, a);
            a = fma((double)xr[3], kv3, a);
            acc[t] = a;
        }
    }
    const double b = (double)bias[e];
#pragma unroll
    for (int t = 0; t < 16; ++t)
        sc[t][e] = 1.0 / (1.0 + exp(-acc[t])) + b;
    __syncthreads();
    if (e < 16) select_f64(&sc[e][0], (int)(t0 + e), out, T);
}

extern "C" void kernel_launch(void* const* d_in, const int* in_sizes, int n_in,
                              void* d_out, int out_size, void* d_ws, size_t ws_size,
                              hipStream_t stream) {
    const float* x    = (const float*)d_in[0];
    const float* wk   = (const float*)d_in[1];
    const float* bias = (const float*)d_in[2];
    float* out = (float*)d_out;
    const int T = in_sizes[0] / HDIM;    // 16384

    if (ws_size < WS_NEED) {   // safety net: exact fp64, no workspace needed
        hipLaunchKernelGGL(moe_gate_f64_full, dim3(T / 16), dim3(256), 0, stream,
                           x, wk, bias, out, T);
        return;
    }

    char*   ws     = (char*)d_ws;
    int*    cnt    = (int*)(ws + WS_CNT_OFF);
    int*    list   = (int*)(ws + WS_LIST_OFF);
    char*   khi    = ws + WS_KHI_OFF;
    char*   klo    = ws + WS_KLO_OFF;
    float*  logits = (float*)(ws + WS_BUF_OFF);
    double* pref   = (double*)(ws + WS_BUF_OFF);  // aliased after gate reads

    hipLaunchKernelGGL(moe_prep,    dim3(224), dim3(256),  0, stream, wk, khi, klo, cnt);
    hipLaunchKernelGGL(moe_main,    dim3(256), dim3(512),  0, stream, x, khi, klo, logits, T);
    hipLaunchKernelGGL(moe_gate,    dim3(T / 64), dim3(256), 0, stream, logits, bias, out, cnt, list, T);
    hipLaunchKernelGGL(moe_refineA, dim3(256), dim3(256),  0, stream, x, wk, pref, cnt, list, T);
    hipLaunchKernelGGL(moe_refineB, dim3(512), dim3(256),  0, stream, x, wk, bias, out, pref, cnt, list, T);
}